// Round 10
// baseline (327.309 us; speedup 1.0000x reference)
//
#include <hip/hip_runtime.h>

#define N_NODES 50000
#define N_EDGES 800000
#define HEADS 8
#define HD 16
#define F 128
#define RPB 16      // rows per block in projection kernel
#define SCAN_B 1024
#define NB1 ((N_NODES + SCAN_B - 1) / SCAN_B)   // 49 scan blocks
#define TILE 8      // edges per k_agg_fused inner tile

// mish(x) = x - 2x/(z^2+1), z = 1+e^x  (native exp + rcp; rcp(inf)=0 -> x)
__device__ __forceinline__ float mish_x(float x) {
    const float ex = __expf(x);
    const float z  = 1.0f + ex;
    const float zz = fmaf(z, z, 1.0f);
    const float r  = __builtin_amdgcn_rcpf(zz);
    return fmaf(-2.0f * x, r, x);
}

// sum across each 8-lane head group (lanes 8h..8h+7), pure-VALU DPP.
__device__ __forceinline__ float head8_sum(float x) {
    int v;
    v = __builtin_amdgcn_update_dpp(0, __float_as_int(x), 0xB1, 0xF, 0xF, true);
    x += __int_as_float(v);                       // + lane^1 (quad perm)
    v = __builtin_amdgcn_update_dpp(0, __float_as_int(x), 0x4E, 0xF, 0xF, true);
    x += __int_as_float(v);                       // + lane^2 (quad perm)
    v = __builtin_amdgcn_update_dpp(0, __float_as_int(x), 0x141, 0xF, 0xF, true);
    x += __int_as_float(v);                       // + other quad (half mirror)
    return x;
}

// ---- K0: transpose both weight matrices: Wt[o][f] = W[f][o] ----
__global__ __launch_bounds__(128) void k_wtrans(
        const float* __restrict__ Ws, const float* __restrict__ Wr,
        float* __restrict__ WtS, float* __restrict__ WtR) {
    const int f = blockIdx.x;            // 0..127
    const int o = threadIdx.x;           // 0..127
    WtS[o * F + f] = Ws[f * F + o];      // coalesced read, scattered write
    WtR[o * F + f] = Wr[f * F + o];
}

// ---- K1: dual projection GEMM (transposed weights) + fused histogram ----
__global__ __launch_bounds__(128) void k_proj_hist(
        const float* __restrict__ nodes,
        const float* __restrict__ WtS, const float* __restrict__ Wsb,
        const float* __restrict__ WtR, const float* __restrict__ Wrb,
        const int* __restrict__ receivers, int* __restrict__ counts,
        float* __restrict__ Ps, float* __restrict__ Pr) {
    __shared__ float rows[RPB][F];
    const int o  = threadIdx.x;
    const int r0 = blockIdx.x * RPB;

    // fire-and-forget histogram atomics; latency hides under the GEMM
    const int ebase = blockIdx.x * 256 + o;
    atomicAdd(counts + receivers[ebase], 1);
    atomicAdd(counts + receivers[ebase + 128], 1);

    for (int i = 0; i < RPB; ++i)
        rows[i][o] = nodes[(r0 + i) * F + o];
    __syncthreads();

    float accs[RPB], accr[RPB];
    const float bs = Wsb[o], br = Wrb[o];
    #pragma unroll
    for (int i = 0; i < RPB; ++i) { accs[i] = bs; accr[i] = br; }

    // per-thread contiguous weight streams (512B each), float4-vectorized
    const float4* ws4p = (const float4*)(WtS + o * F);
    const float4* wr4p = (const float4*)(WtR + o * F);
    for (int f4 = 0; f4 < F / 4; ++f4) {
        const float4 ws4 = ws4p[f4];
        const float4 wr4 = wr4p[f4];
        #pragma unroll
        for (int i = 0; i < RPB; ++i) {
            const float4 rv = *(const float4*)(&rows[i][f4 << 2]);  // b128 bcast
            accs[i] = fmaf(rv.x, ws4.x, accs[i]);
            accs[i] = fmaf(rv.y, ws4.y, accs[i]);
            accs[i] = fmaf(rv.z, ws4.z, accs[i]);
            accs[i] = fmaf(rv.w, ws4.w, accs[i]);
            accr[i] = fmaf(rv.x, wr4.x, accr[i]);
            accr[i] = fmaf(rv.y, wr4.y, accr[i]);
            accr[i] = fmaf(rv.z, wr4.z, accr[i]);
            accr[i] = fmaf(rv.w, wr4.w, accr[i]);
        }
    }
    #pragma unroll
    for (int i = 0; i < RPB; ++i) {
        Ps[(r0 + i) * F + o] = accs[i];
        Pr[(r0 + i) * F + o] = accr[i];
    }
}

// ---- scan1: block-local exclusive scan of counts + per-block totals ----
__global__ __launch_bounds__(1024) void k_scan1(
        const int* __restrict__ counts, int* __restrict__ starts,
        int* __restrict__ partials) {
    __shared__ int buf[SCAN_B];
    const int i = blockIdx.x * SCAN_B + threadIdx.x;
    const int v = (i < N_NODES) ? counts[i] : 0;
    buf[threadIdx.x] = v;
    __syncthreads();
    for (int off = 1; off < SCAN_B; off <<= 1) {
        const int t = (threadIdx.x >= (unsigned)off) ? buf[threadIdx.x - off] : 0;
        __syncthreads();
        buf[threadIdx.x] += t;
        __syncthreads();
    }
    if (i < N_NODES) starts[i] = buf[threadIdx.x] - v;   // block-local exclusive
    if (threadIdx.x == SCAN_B - 1) partials[blockIdx.x] = buf[SCAN_B - 1];
}

// ---- fill: global start = starts[r] + prefix(partials)[r>>10] ----
__global__ __launch_bounds__(256) void k_fill(
        const int* __restrict__ senders, const int* __restrict__ receivers,
        const int* __restrict__ starts, const int* __restrict__ partials,
        int* __restrict__ cursor, int* __restrict__ slist) {
    __shared__ int off_lds[NB1];
    if (threadIdx.x < 64) {
        const int j = (int)threadIdx.x;
        const int v = (j < NB1) ? partials[j] : 0;
        int incl = v;
        #pragma unroll
        for (int d = 1; d < 64; d <<= 1) {
            const int u = __shfl_up(incl, d);
            if (j >= d) incl += u;
        }
        if (j < NB1) off_lds[j] = incl - v;              // exclusive
    }
    __syncthreads();
    const int e = blockIdx.x * 256 + (int)threadIdx.x;   // 3125*256 == N_EDGES
    const int r = receivers[e];
    const int pos = atomicAdd(cursor + r, 1);
    slist[starts[r] + off_lds[r >> 10] + pos] = senders[e];
}

// ---- K4: fused logits + no-max softmax + aggregation.
//      ONE WAVE per node, 2 dims per lane (float2); 4 nodes per 256-block. ----
__global__ __launch_bounds__(256) void k_agg_fused(
        const int* __restrict__ starts, const int* __restrict__ counts,
        const int* __restrict__ partials, const int* __restrict__ slist,
        const float* __restrict__ Ps, const float* __restrict__ Pr,
        const float* __restrict__ attn_k, float* __restrict__ out) {
    const int lane = (int)threadIdx.x & 63;
    const int n = __builtin_amdgcn_readfirstlane(
                      blockIdx.x * 4 + ((int)threadIdx.x >> 6));
    const int d0 = lane << 1;                 // dims d0, d0+1; head = lane>>3

    // offset of this node's superblock: sum(partials[j] for j < n>>10)
    const int sb = n >> 10;
    int v = (lane < sb) ? partials[lane] : 0;
    v += __shfl_xor(v, 1);  v += __shfl_xor(v, 2);  v += __shfl_xor(v, 4);
    v += __shfl_xor(v, 8);  v += __shfl_xor(v, 16); v += __shfl_xor(v, 32);

    const int e0 = starts[n] + v;
    const int e1 = e0 + counts[n];
    const float2 pr2 = *(const float2*)(Pr + (size_t)n * F + d0);
    const float2 ak2 = *(const float2*)(attn_k + (d0 & 15));

    float den = 0.0f, ax = 0.0f, ay = 0.0f;

    if (e1 > e0) {
        float2 cur[TILE], nxt[TILE];
        #pragma unroll
        for (int k = 0; k < TILE; ++k) {
            const int idx = (e0 + k < e1) ? e0 + k : e1 - 1;
            cur[k] = *(const float2*)(Ps + (size_t)slist[idx] * F + d0);
        }
        for (int i = e0; i < e1; i += TILE) {
            const bool more = (i + TILE) < e1;    // wave-uniform
            if (more) {
                #pragma unroll
                for (int k = 0; k < TILE; ++k) {
                    const int idx = (i + TILE + k < e1) ? i + TILE + k : e1 - 1;
                    nxt[k] = *(const float2*)(Ps + (size_t)slist[idx] * F + d0);
                }
            }
            #pragma unroll
            for (int k = 0; k < TILE; ++k) {
                const float mi = mish_x(cur[k].x + pr2.x) * ak2.x
                               + mish_x(cur[k].y + pr2.y) * ak2.y;
                const float s = head8_sum(mi);
                const float w = (i + k < e1) ? __expf(s) : 0.0f;
                den += w;
                ax = fmaf(w, cur[k].x, ax);
                ay = fmaf(w, cur[k].y, ay);
            }
            if (more) {
                #pragma unroll
                for (int k = 0; k < TILE; ++k) cur[k] = nxt[k];
            }
        }
    }
    const float inv = __builtin_amdgcn_rcpf(den);
    float2 o2;
    o2.x = (den > 0.0f) ? ax * inv : 0.0f;
    o2.y = (den > 0.0f) ? ay * inv : 0.0f;
    *(float2*)(out + (size_t)n * F + d0) = o2;
}

extern "C" void kernel_launch(void* const* d_in, const int* in_sizes, int n_in,
                              void* d_out, int out_size, void* d_ws, size_t ws_size,
                              hipStream_t stream) {
    const float* nodes     = (const float*)d_in[0];
    const int*   senders   = (const int*)  d_in[1];
    const int*   receivers = (const int*)  d_in[2];
    const float* Wsk       = (const float*)d_in[3];
    const float* Wsb       = (const float*)d_in[4];
    const float* Wrk       = (const float*)d_in[5];
    const float* Wrb       = (const float*)d_in[6];
    const float* attnk     = (const float*)d_in[7];
    float* out = (float*)d_out;

    // workspace layout
    float* Ps       = (float*)d_ws;                          // N*F
    float* Pr       = Ps + (size_t)N_NODES * F;              // N*F
    int*   slist    = (int*)(Pr + (size_t)N_NODES * F);      // E
    int*   counts   = slist + N_EDGES;                       // N
    int*   cursor   = counts + N_NODES;                      // N
    int*   starts   = cursor + N_NODES;                      // N (block-local)
    int*   partials = starts + N_NODES + 1;                  // NB1 (<64)
    float* WtS      = (float*)(partials + 64);               // F*F
    float* WtR      = WtS + F * F;                           // F*F

    // one memset zeroes both counts and cursor (adjacent)
    hipMemsetAsync(counts, 0, 2 * N_NODES * sizeof(int), stream);

    k_wtrans<<<F, 128, 0, stream>>>(Wsk, Wrk, WtS, WtR);
    k_proj_hist<<<N_NODES / RPB, 128, 0, stream>>>(nodes, WtS, Wsb, WtR, Wrb,
                                                   receivers, counts, Ps, Pr);
    k_scan1<<<NB1, SCAN_B, 0, stream>>>(counts, starts, partials);
    k_fill<<<N_EDGES / 256, 256, 0, stream>>>(senders, receivers, starts,
                                              partials, cursor, slist);
    k_agg_fused<<<N_NODES / 4, 256, 0, stream>>>(starts, counts, partials,
                                                 slist, Ps, Pr, attnk, out);
}

// Round 11
// 266.835 us; speedup vs baseline: 1.2266x; 1.2266x over previous
//
#include <hip/hip_runtime.h>

#define N_NODES 50000
#define N_EDGES 800000
#define HEADS 8
#define HD 16
#define F 128
#define RPB 16      // rows per block in projection kernel
#define RPT 8       // rows per thread (256 threads: 2 row-halves x 128 cols)
#define SCAN_B 1024
#define NB1 ((N_NODES + SCAN_B - 1) / SCAN_B)   // 49 scan blocks
#define TILE 8      // edges per k_agg_fused inner tile

// mish(x) = x - 2x/(z^2+1), z = 1+e^x  (native exp + rcp; rcp(inf)=0 -> x)
__device__ __forceinline__ float mish_x(float x) {
    const float ex = __expf(x);
    const float z  = 1.0f + ex;
    const float zz = fmaf(z, z, 1.0f);
    const float r  = __builtin_amdgcn_rcpf(zz);
    return fmaf(-2.0f * x, r, x);
}

// sum across each 8-lane head group (lanes 8h..8h+7), pure-VALU DPP.
__device__ __forceinline__ float head8_sum(float x) {
    int v;
    v = __builtin_amdgcn_update_dpp(0, __float_as_int(x), 0xB1, 0xF, 0xF, true);
    x += __int_as_float(v);                       // + lane^1 (quad perm)
    v = __builtin_amdgcn_update_dpp(0, __float_as_int(x), 0x4E, 0xF, 0xF, true);
    x += __int_as_float(v);                       // + lane^2 (quad perm)
    v = __builtin_amdgcn_update_dpp(0, __float_as_int(x), 0x141, 0xF, 0xF, true);
    x += __int_as_float(v);                       // + other quad (half mirror)
    return x;
}

// ---- K1: dual projection GEMM + fused receiver histogram.
//      256 threads: o = tid&127 (output col), half = tid>>7 (row half).
//      Weights read coalesced (Ws[f*F+o], consecutive across lanes);
//      node rows read from LDS as b128 broadcasts (wave-uniform addr). ----
__global__ __launch_bounds__(256) void k_proj_hist(
        const float* __restrict__ nodes,
        const float* __restrict__ Ws, const float* __restrict__ Wsb,
        const float* __restrict__ Wr, const float* __restrict__ Wrb,
        const int* __restrict__ receivers, int* __restrict__ counts,
        float* __restrict__ Ps, float* __restrict__ Pr) {
    __shared__ float rows[RPB][F];
    const int tid  = (int)threadIdx.x;
    const int o    = tid & 127;
    const int half = tid >> 7;               // 0 or 1
    const int r0   = blockIdx.x * RPB;

    // fire-and-forget histogram atomic; latency hides under the GEMM
    atomicAdd(counts + receivers[blockIdx.x * 256 + tid], 1);

    for (int i = half; i < RPB; i += 2)
        rows[i][o] = nodes[(r0 + i) * F + o];
    __syncthreads();

    float accs[RPT], accr[RPT];
    const float bs = Wsb[o], br = Wrb[o];
    #pragma unroll
    for (int i = 0; i < RPT; ++i) { accs[i] = bs; accr[i] = br; }

    const int rbase = half * RPT;
    for (int f4 = 0; f4 < F / 4; ++f4) {
        const int f = f4 << 2;
        // coalesced weight loads (4 dwords per matrix, stride F across f)
        float4 ws4, wr4;
        ws4.x = Ws[(f + 0) * F + o];  ws4.y = Ws[(f + 1) * F + o];
        ws4.z = Ws[(f + 2) * F + o];  ws4.w = Ws[(f + 3) * F + o];
        wr4.x = Wr[(f + 0) * F + o];  wr4.y = Wr[(f + 1) * F + o];
        wr4.z = Wr[(f + 2) * F + o];  wr4.w = Wr[(f + 3) * F + o];
        #pragma unroll
        for (int i = 0; i < RPT; ++i) {
            const float4 rv = *(const float4*)(&rows[rbase + i][f]); // b128 bcast
            accs[i] = fmaf(rv.x, ws4.x, accs[i]);
            accs[i] = fmaf(rv.y, ws4.y, accs[i]);
            accs[i] = fmaf(rv.z, ws4.z, accs[i]);
            accs[i] = fmaf(rv.w, ws4.w, accs[i]);
            accr[i] = fmaf(rv.x, wr4.x, accr[i]);
            accr[i] = fmaf(rv.y, wr4.y, accr[i]);
            accr[i] = fmaf(rv.z, wr4.z, accr[i]);
            accr[i] = fmaf(rv.w, wr4.w, accr[i]);
        }
    }
    #pragma unroll
    for (int i = 0; i < RPT; ++i) {
        Ps[(r0 + rbase + i) * F + o] = accs[i];
        Pr[(r0 + rbase + i) * F + o] = accr[i];
    }
}

// ---- scan1: block-local exclusive scan of counts + per-block totals ----
__global__ __launch_bounds__(1024) void k_scan1(
        const int* __restrict__ counts, int* __restrict__ starts,
        int* __restrict__ partials) {
    __shared__ int buf[SCAN_B];
    const int i = blockIdx.x * SCAN_B + threadIdx.x;
    const int v = (i < N_NODES) ? counts[i] : 0;
    buf[threadIdx.x] = v;
    __syncthreads();
    for (int off = 1; off < SCAN_B; off <<= 1) {
        const int t = (threadIdx.x >= (unsigned)off) ? buf[threadIdx.x - off] : 0;
        __syncthreads();
        buf[threadIdx.x] += t;
        __syncthreads();
    }
    if (i < N_NODES) starts[i] = buf[threadIdx.x] - v;   // block-local exclusive
    if (threadIdx.x == SCAN_B - 1) partials[blockIdx.x] = buf[SCAN_B - 1];
}

// ---- fill: global start = starts[r] + prefix(partials)[r>>10] ----
__global__ __launch_bounds__(256) void k_fill(
        const int* __restrict__ senders, const int* __restrict__ receivers,
        const int* __restrict__ starts, const int* __restrict__ partials,
        int* __restrict__ cursor, int* __restrict__ slist) {
    __shared__ int off_lds[NB1];
    if (threadIdx.x < 64) {
        const int j = (int)threadIdx.x;
        const int v = (j < NB1) ? partials[j] : 0;
        int incl = v;
        #pragma unroll
        for (int d = 1; d < 64; d <<= 1) {
            const int u = __shfl_up(incl, d);
            if (j >= d) incl += u;
        }
        if (j < NB1) off_lds[j] = incl - v;              // exclusive
    }
    __syncthreads();
    const int e = blockIdx.x * 256 + (int)threadIdx.x;   // 3125*256 == N_EDGES
    const int r = receivers[e];
    const int pos = atomicAdd(cursor + r, 1);
    slist[starts[r] + off_lds[r >> 10] + pos] = senders[e];
}

// ---- K4: fused logits + no-max softmax + aggregation.
//      ONE WAVE per node, 2 dims per lane (float2); 4 nodes per 256-block. ----
__global__ __launch_bounds__(256) void k_agg_fused(
        const int* __restrict__ starts, const int* __restrict__ counts,
        const int* __restrict__ partials, const int* __restrict__ slist,
        const float* __restrict__ Ps, const float* __restrict__ Pr,
        const float* __restrict__ attn_k, float* __restrict__ out) {
    const int lane = (int)threadIdx.x & 63;
    const int n = __builtin_amdgcn_readfirstlane(
                      blockIdx.x * 4 + ((int)threadIdx.x >> 6));
    const int d0 = lane << 1;                 // dims d0, d0+1; head = lane>>3

    // offset of this node's superblock: sum(partials[j] for j < n>>10)
    const int sb = n >> 10;
    int v = (lane < sb) ? partials[lane] : 0;
    v += __shfl_xor(v, 1);  v += __shfl_xor(v, 2);  v += __shfl_xor(v, 4);
    v += __shfl_xor(v, 8);  v += __shfl_xor(v, 16); v += __shfl_xor(v, 32);

    const int e0 = starts[n] + v;
    const int e1 = e0 + counts[n];
    const float2 pr2 = *(const float2*)(Pr + (size_t)n * F + d0);
    const float2 ak2 = *(const float2*)(attn_k + (d0 & 15));

    float den = 0.0f, ax = 0.0f, ay = 0.0f;

    if (e1 > e0) {
        float2 cur[TILE], nxt[TILE];
        #pragma unroll
        for (int k = 0; k < TILE; ++k) {
            const int idx = (e0 + k < e1) ? e0 + k : e1 - 1;
            cur[k] = *(const float2*)(Ps + (size_t)slist[idx] * F + d0);
        }
        for (int i = e0; i < e1; i += TILE) {
            const bool more = (i + TILE) < e1;    // wave-uniform
            if (more) {
                #pragma unroll
                for (int k = 0; k < TILE; ++k) {
                    const int idx = (i + TILE + k < e1) ? i + TILE + k : e1 - 1;
                    nxt[k] = *(const float2*)(Ps + (size_t)slist[idx] * F + d0);
                }
            }
            #pragma unroll
            for (int k = 0; k < TILE; ++k) {
                const float mi = mish_x(cur[k].x + pr2.x) * ak2.x
                               + mish_x(cur[k].y + pr2.y) * ak2.y;
                const float s = head8_sum(mi);
                const float w = (i + k < e1) ? __expf(s) : 0.0f;
                den += w;
                ax = fmaf(w, cur[k].x, ax);
                ay = fmaf(w, cur[k].y, ay);
            }
            if (more) {
                #pragma unroll
                for (int k = 0; k < TILE; ++k) cur[k] = nxt[k];
            }
        }
    }
    const float inv = __builtin_amdgcn_rcpf(den);
    float2 o2;
    o2.x = (den > 0.0f) ? ax * inv : 0.0f;
    o2.y = (den > 0.0f) ? ay * inv : 0.0f;
    *(float2*)(out + (size_t)n * F + d0) = o2;
}

extern "C" void kernel_launch(void* const* d_in, const int* in_sizes, int n_in,
                              void* d_out, int out_size, void* d_ws, size_t ws_size,
                              hipStream_t stream) {
    const float* nodes     = (const float*)d_in[0];
    const int*   senders   = (const int*)  d_in[1];
    const int*   receivers = (const int*)  d_in[2];
    const float* Wsk       = (const float*)d_in[3];
    const float* Wsb       = (const float*)d_in[4];
    const float* Wrk       = (const float*)d_in[5];
    const float* Wrb       = (const float*)d_in[6];
    const float* attnk     = (const float*)d_in[7];
    float* out = (float*)d_out;

    // workspace layout
    float* Ps       = (float*)d_ws;                          // N*F
    float* Pr       = Ps + (size_t)N_NODES * F;              // N*F
    int*   slist    = (int*)(Pr + (size_t)N_NODES * F);      // E
    int*   counts   = slist + N_EDGES;                       // N
    int*   cursor   = counts + N_NODES;                      // N
    int*   starts   = cursor + N_NODES;                      // N (block-local)
    int*   partials = starts + N_NODES + 1;                  // NB1 (<64)

    // one memset zeroes both counts and cursor (adjacent)
    hipMemsetAsync(counts, 0, 2 * N_NODES * sizeof(int), stream);

    k_proj_hist<<<N_NODES / RPB, 256, 0, stream>>>(nodes, Wsk, Wsb, Wrk, Wrb,
                                                   receivers, counts, Ps, Pr);
    k_scan1<<<NB1, SCAN_B, 0, stream>>>(counts, starts, partials);
    k_fill<<<N_EDGES / 256, 256, 0, stream>>>(senders, receivers, starts,
                                              partials, cursor, slist);
    k_agg_fused<<<N_NODES / 4, 256, 0, stream>>>(starts, counts, partials,
                                                 slist, Ps, Pr, attnk, out);
}

// Round 16
// 260.332 us; speedup vs baseline: 1.2573x; 1.0250x over previous
//
#include <hip/hip_runtime.h>

#define N_NODES 50000
#define N_EDGES 800000
#define HEADS 8
#define HD 16
#define F 128
#define RPB 32      // rows per block in projection kernel
#define RPT 16      // rows per thread (256 threads: 2 row-halves x 128 cols)
#define PROJ_B ((N_NODES + RPB - 1) / RPB)      // 1563 proj blocks
#define SCAN_B 1024
#define NB1 ((N_NODES + SCAN_B - 1) / SCAN_B)   // 49 scan blocks
#define TILE 8      // edges per k_agg_fused inner tile

// mish(x) = x - 2x/(z^2+1), z = 1+e^x  (native exp + rcp; rcp(inf)=0 -> x)
__device__ __forceinline__ float mish_x(float x) {
    const float ex = __expf(x);
    const float z  = 1.0f + ex;
    const float zz = fmaf(z, z, 1.0f);
    const float r  = __builtin_amdgcn_rcpf(zz);
    return fmaf(-2.0f * x, r, x);
}

// sum across each 8-lane head group (lanes 8h..8h+7), pure-VALU DPP.
__device__ __forceinline__ float head8_sum(float x) {
    int v;
    v = __builtin_amdgcn_update_dpp(0, __float_as_int(x), 0xB1, 0xF, 0xF, true);
    x += __int_as_float(v);                       // + lane^1 (quad perm)
    v = __builtin_amdgcn_update_dpp(0, __float_as_int(x), 0x4E, 0xF, 0xF, true);
    x += __int_as_float(v);                       // + lane^2 (quad perm)
    v = __builtin_amdgcn_update_dpp(0, __float_as_int(x), 0x141, 0xF, 0xF, true);
    x += __int_as_float(v);                       // + other quad (half mirror)
    return x;
}

// ---- K1: dual projection GEMM + fused histogram-with-slot.
//      256 threads: o = tid&127 (output col), half = tid>>7 (row half).
//      Each thread also claims slots for 2 edges (atomic return value =
//      within-receiver position) -> k_fill needs no atomics. ----
__global__ __launch_bounds__(256) void k_proj_hist(
        const float* __restrict__ nodes,
        const float* __restrict__ Ws, const float* __restrict__ Wsb,
        const float* __restrict__ Wr, const float* __restrict__ Wrb,
        const int* __restrict__ receivers, int* __restrict__ counts,
        int* __restrict__ slot,
        float* __restrict__ Ps, float* __restrict__ Pr) {
    __shared__ float rows[RPB][F];
    const int tid  = (int)threadIdx.x;
    const int o    = tid & 127;
    const int half = tid >> 7;               // 0 or 1
    const int r0   = blockIdx.x * RPB;

    // slot assignment for 2 edges; atomic latency hides under the GEMM
    const int e = blockIdx.x * 512 + tid;
    if (e < N_EDGES)       slot[e]       = atomicAdd(counts + receivers[e], 1);
    if (e + 256 < N_EDGES) slot[e + 256] = atomicAdd(counts + receivers[e + 256], 1);

    for (int i = half; i < RPB; i += 2) {
        const int rr = r0 + i;
        rows[i][o] = (rr < N_NODES) ? nodes[rr * F + o] : 0.0f;
    }
    __syncthreads();

    float accs[RPT], accr[RPT];
    const float bs = Wsb[o], br = Wrb[o];
    #pragma unroll
    for (int i = 0; i < RPT; ++i) { accs[i] = bs; accr[i] = br; }

    const int rbase = half * RPT;
    for (int f4 = 0; f4 < F / 4; ++f4) {
        const int f = f4 << 2;
        // coalesced weight loads (4 dwords per matrix, stride F across f)
        float4 ws4, wr4;
        ws4.x = Ws[(f + 0) * F + o];  ws4.y = Ws[(f + 1) * F + o];
        ws4.z = Ws[(f + 2) * F + o];  ws4.w = Ws[(f + 3) * F + o];
        wr4.x = Wr[(f + 0) * F + o];  wr4.y = Wr[(f + 1) * F + o];
        wr4.z = Wr[(f + 2) * F + o];  wr4.w = Wr[(f + 3) * F + o];
        #pragma unroll
        for (int i = 0; i < RPT; ++i) {
            const float4 rv = *(const float4*)(&rows[rbase + i][f]); // b128 bcast
            accs[i] = fmaf(rv.x, ws4.x, accs[i]);
            accs[i] = fmaf(rv.y, ws4.y, accs[i]);
            accs[i] = fmaf(rv.z, ws4.z, accs[i]);
            accs[i] = fmaf(rv.w, ws4.w, accs[i]);
            accr[i] = fmaf(rv.x, wr4.x, accr[i]);
            accr[i] = fmaf(rv.y, wr4.y, accr[i]);
            accr[i] = fmaf(rv.z, wr4.z, accr[i]);
            accr[i] = fmaf(rv.w, wr4.w, accr[i]);
        }
    }
    #pragma unroll
    for (int i = 0; i < RPT; ++i) {
        const int rr = r0 + rbase + i;
        if (rr < N_NODES) {
            Ps[rr * F + o] = accs[i];
            Pr[rr * F + o] = accr[i];
        }
    }
}

// ---- scan1: block-local exclusive scan of counts + per-block totals ----
__global__ __launch_bounds__(1024) void k_scan1(
        const int* __restrict__ counts, int* __restrict__ starts,
        int* __restrict__ partials) {
    __shared__ int buf[SCAN_B];
    const int i = blockIdx.x * SCAN_B + threadIdx.x;
    const int v = (i < N_NODES) ? counts[i] : 0;
    buf[threadIdx.x] = v;
    __syncthreads();
    for (int off = 1; off < SCAN_B; off <<= 1) {
        const int t = (threadIdx.x >= (unsigned)off) ? buf[threadIdx.x - off] : 0;
        __syncthreads();
        buf[threadIdx.x] += t;
        __syncthreads();
    }
    if (i < N_NODES) starts[i] = buf[threadIdx.x] - v;   // block-local exclusive
    if (threadIdx.x == SCAN_B - 1) partials[blockIdx.x] = buf[SCAN_B - 1];
}

// ---- fill: atomic-free scatter using precomputed slots ----
__global__ __launch_bounds__(256) void k_fill(
        const int* __restrict__ senders, const int* __restrict__ receivers,
        const int* __restrict__ starts, const int* __restrict__ partials,
        const int* __restrict__ slot, int* __restrict__ slist) {
    __shared__ int off_lds[NB1];
    if (threadIdx.x < 64) {
        const int j = (int)threadIdx.x;
        const int v = (j < NB1) ? partials[j] : 0;
        int incl = v;
        #pragma unroll
        for (int d = 1; d < 64; d <<= 1) {
            const int u = __shfl_up(incl, d);
            if (j >= d) incl += u;
        }
        if (j < NB1) off_lds[j] = incl - v;              // exclusive
    }
    __syncthreads();
    const int e = blockIdx.x * 256 + (int)threadIdx.x;   // 3125*256 == N_EDGES
    const int r = receivers[e];
    slist[starts[r] + off_lds[r >> 10] + slot[e]] = senders[e];
}

// ---- K4: fused logits + no-max softmax + aggregation.
//      ONE WAVE per node, 2 dims per lane (float2); 4 nodes per 256-block. ----
__global__ __launch_bounds__(256) void k_agg_fused(
        const int* __restrict__ starts, const int* __restrict__ counts,
        const int* __restrict__ partials, const int* __restrict__ slist,
        const float* __restrict__ Ps, const float* __restrict__ Pr,
        const float* __restrict__ attn_k, float* __restrict__ out) {
    const int lane = (int)threadIdx.x & 63;
    const int n = __builtin_amdgcn_readfirstlane(
                      blockIdx.x * 4 + ((int)threadIdx.x >> 6));
    const int d0 = lane << 1;                 // dims d0, d0+1; head = lane>>3

    // offset of this node's superblock: sum(partials[j] for j < n>>10)
    const int sb = n >> 10;
    int v = (lane < sb) ? partials[lane] : 0;
    v += __shfl_xor(v, 1);  v += __shfl_xor(v, 2);  v += __shfl_xor(v, 4);
    v += __shfl_xor(v, 8);  v += __shfl_xor(v, 16); v += __shfl_xor(v, 32);

    const int e0 = starts[n] + v;
    const int e1 = e0 + counts[n];
    const float2 pr2 = *(const float2*)(Pr + (size_t)n * F + d0);
    const float2 ak2 = *(const float2*)(attn_k + (d0 & 15));

    float den = 0.0f, ax = 0.0f, ay = 0.0f;

    if (e1 > e0) {
        float2 cur[TILE], nxt[TILE];
        #pragma unroll
        for (int k = 0; k < TILE; ++k) {
            const int idx = (e0 + k < e1) ? e0 + k : e1 - 1;
            cur[k] = *(const float2*)(Ps + (size_t)slist[idx] * F + d0);
        }
        for (int i = e0; i < e1; i += TILE) {
            const bool more = (i + TILE) < e1;    // wave-uniform
            if (more) {
                #pragma unroll
                for (int k = 0; k < TILE; ++k) {
                    const int idx = (i + TILE + k < e1) ? i + TILE + k : e1 - 1;
                    nxt[k] = *(const float2*)(Ps + (size_t)slist[idx] * F + d0);
                }
            }
            #pragma unroll
            for (int k = 0; k < TILE; ++k) {
                const float mi = mish_x(cur[k].x + pr2.x) * ak2.x
                               + mish_x(cur[k].y + pr2.y) * ak2.y;
                const float s = head8_sum(mi);
                const float w = (i + k < e1) ? __expf(s) : 0.0f;
                den += w;
                ax = fmaf(w, cur[k].x, ax);
                ay = fmaf(w, cur[k].y, ay);
            }
            if (more) {
                #pragma unroll
                for (int k = 0; k < TILE; ++k) cur[k] = nxt[k];
            }
        }
    }
    const float inv = __builtin_amdgcn_rcpf(den);
    float2 o2;
    o2.x = (den > 0.0f) ? ax * inv : 0.0f;
    o2.y = (den > 0.0f) ? ay * inv : 0.0f;
    *(float2*)(out + (size_t)n * F + d0) = o2;
}

extern "C" void kernel_launch(void* const* d_in, const int* in_sizes, int n_in,
                              void* d_out, int out_size, void* d_ws, size_t ws_size,
                              hipStream_t stream) {
    const float* nodes     = (const float*)d_in[0];
    const int*   senders   = (const int*)  d_in[1];
    const int*   receivers = (const int*)  d_in[2];
    const float* Wsk       = (const float*)d_in[3];
    const float* Wsb       = (const float*)d_in[4];
    const float* Wrk       = (const float*)d_in[5];
    const float* Wrb       = (const float*)d_in[6];
    const float* attnk     = (const float*)d_in[7];
    float* out = (float*)d_out;

    // workspace layout
    float* Ps       = (float*)d_ws;                          // N*F
    float* Pr       = Ps + (size_t)N_NODES * F;              // N*F
    int*   slist    = (int*)(Pr + (size_t)N_NODES * F);      // E
    int*   slot     = slist + N_EDGES;                       // E
    int*   counts   = slot + N_EDGES;                        // N
    int*   starts   = counts + N_NODES;                      // N+1
    int*   partials = starts + N_NODES + 1;                  // NB1 (<64)

    hipMemsetAsync(counts, 0, N_NODES * sizeof(int), stream);

    k_proj_hist<<<PROJ_B, 256, 0, stream>>>(nodes, Wsk, Wsb, Wrk, Wrb,
                                            receivers, counts, slot, Ps, Pr);
    k_scan1<<<NB1, SCAN_B, 0, stream>>>(counts, starts, partials);
    k_fill<<<N_EDGES / 256, 256, 0, stream>>>(senders, receivers, starts,
                                              partials, slot, slist);
    k_agg_fused<<<N_NODES / 4, 256, 0, stream>>>(starts, counts, partials,
                                                 slist, Ps, Pr, attnk, out);
}